// Round 2
// baseline (129.409 us; speedup 1.0000x reference)
//
#include <hip/hip_runtime.h>
#include <math.h>

#define NB 2048
#define LL 200
#define DD 64
#define CC 9
#define HH 16

__global__ __launch_bounds__(256) void din_fwd(
    const int* __restrict__ user_inputs,     // [B]
    const int* __restrict__ record_inputs,   // [B,L]
    const int* __restrict__ item_inputs,     // [B]
    const int* __restrict__ item_cat,        // [NUM_ITEMS]
    const float* __restrict__ user_emb,      // [NU,D]
    const float* __restrict__ item_emb,      // [NI,D]
    const float* __restrict__ W1,            // [C,H,2D]
    const float* __restrict__ b1,            // [C,H]
    const float* __restrict__ W2,            // [C,1,H]
    const float* __restrict__ b2,            // [C,1]
    const float* __restrict__ Wt1,           // [H,2D]
    const float* __restrict__ bt1,           // [H]
    const float* __restrict__ Wt2,           // [1,H]
    const float* __restrict__ bt2,           // [1]
    float* __restrict__ out)                 // [B]
{
  const int b = blockIdx.x;
  const int t = threadIdx.x;

  __shared__ float u_s[DD];
  __shared__ float pre_s[CC][HH];
  __shared__ int   cat0[LL];
  __shared__ int   rec0[LL];
  __shared__ int   scat[LL];
  __shared__ int   srow[LL];
  __shared__ float s_s[LL];
  __shared__ float w_s[LL];
  __shared__ int   cstart[CC + 1];
  __shared__ float cinv[CC];
  __shared__ int   cnt_s[CC];
  __shared__ float gvec_s[CC][DD];
  __shared__ float h2_s[CC][HH];
  __shared__ float w2_s[CC];

  // ---- Phase 0a: global loads + zero counters (no atomics yet) ----
  int r = -1, c0 = -1;
  if (t < LL) {
    r = record_inputs[b * LL + t];
    if (r >= 0) c0 = item_cat[r];
  }
  if (t < DD) u_s[t] = user_emb[(size_t)user_inputs[b] * DD + t];
  if (t < CC) cnt_s[t] = 0;
  __syncthreads();   // cnt_s zeroed by wave 0 BEFORE any wave's atomicAdd

  // ---- Phase 0b: deterministic integer counting ----
  if (t < LL) {
    rec0[t] = r;
    cat0[t] = c0;
    if (c0 >= 0) atomicAdd(&cnt_s[c0], 1);
  }
  __syncthreads();

  // prefix sum (9 elements, thread 0)
  if (t == 0) {
    int acc = 0;
    for (int c = 0; c < CC; ++c) { cstart[c] = acc; acc += cnt_s[c]; }
    cstart[CC] = acc;
  }
  __syncthreads();

  // ---- stable rank-based scatter (deterministic) + pre = W1u*u + b1 ----
  if (t < LL) {
    int c = cat0[t];
    if (c >= 0) {
      int rank = 0;
      for (int q = 0; q < t; ++q) rank += (cat0[q] == c) ? 1 : 0;
      int pos = cstart[c] + rank;
      scat[pos] = c;
      srow[pos] = rec0[t];
    }
  }
  if (t < CC * HH) {
    int c = t / HH, j = t % HH;
    const float* wp = &W1[(size_t)(c * HH + j) * (2 * DD)];
    float acc = b1[c * HH + j];
    #pragma unroll 8
    for (int d = 0; d < DD; ++d) acc += wp[d] * u_s[d];
    pre_s[c][j] = acc;
  }
  __syncthreads();

  const int nvalid = cstart[CC];

  // ---- Phase 1: per-item single-category MLP score ----
  if (t < nvalid) {
    int c = scat[t];
    int row = srow[t];
    const float4* ep = (const float4*)&item_emb[(size_t)row * DD];
    float4 e[16];
    #pragma unroll
    for (int i = 0; i < 16; ++i) e[i] = ep[i];

    float s = b2[c];
    #pragma unroll 2
    for (int j = 0; j < HH; ++j) {
      const float4* wp = (const float4*)&W1[(size_t)(c * HH + j) * (2 * DD) + DD];
      float acc = pre_s[c][j];
      #pragma unroll
      for (int i = 0; i < 16; ++i) {
        float4 wv = wp[i];
        acc += wv.x * e[i].x + wv.y * e[i].y + wv.z * e[i].z + wv.w * e[i].w;
      }
      acc = fmaxf(acc, 0.f);
      s += W2[c * HH + j] * acc;
    }
    s_s[t] = s;
  }
  __syncthreads();

  // ---- Phase 2: masked softmax per category (small ranges) ----
  if (t < CC) {
    int i0 = cstart[t], i1 = cstart[t + 1];
    float m = -INFINITY;
    for (int i = i0; i < i1; ++i) m = fmaxf(m, s_s[i]);
    float sum = 0.f;
    for (int i = i0; i < i1; ++i) {
      float z = expf(s_s[i] - m);
      w_s[i] = z;
      sum += z;
    }
    cinv[t] = 1.f / fmaxf(sum, 1e-30f);
  }
  __syncthreads();

  // ---- Phase 3: gvec[c][d] = inv_c * sum_i z_i * e_i[d]  (wave per cat group) ----
  {
    int wave = t >> 6, lane = t & 63;
    for (int c = wave; c < CC; c += 4) {
      float acc = 0.f;
      int i0 = cstart[c], i1 = cstart[c + 1];
      for (int i = i0; i < i1; ++i) {
        acc += w_s[i] * item_emb[(size_t)srow[i] * DD + lane];
      }
      gvec_s[c][lane] = acc * cinv[c];   // empty cat: 0 * big = 0
    }
  }
  __syncthreads();

  // ---- Phase 4: top-level attention ----
  if (t < CC * HH) {
    int c = t / HH, j = t % HH;
    const float* wp = &Wt1[(size_t)j * (2 * DD)];
    float acc = bt1[j];
    #pragma unroll 8
    for (int d = 0; d < DD; ++d) acc += wp[d] * u_s[d];
    #pragma unroll 8
    for (int d = 0; d < DD; ++d) acc += wp[DD + d] * gvec_s[c][d];
    h2_s[c][j] = fmaxf(acc, 0.f);
  }
  __syncthreads();

  if (t == 0) {
    float s2[CC];
    float m = -INFINITY;
    #pragma unroll
    for (int c = 0; c < CC; ++c) {
      float acc = bt2[0];
      #pragma unroll
      for (int j = 0; j < HH; ++j) acc += Wt2[j] * h2_s[c][j];
      s2[c] = acc;
      if (cnt_s[c] > 0) m = fmaxf(m, acc);
    }
    if (m == -INFINITY) m = 0.f;
    float sum = 0.f;
    float z2[CC];
    #pragma unroll
    for (int c = 0; c < CC; ++c) {
      z2[c] = (cnt_s[c] > 0) ? expf(s2[c] - m) : 0.f;
      sum += z2[c];
    }
    float inv = 1.f / fmaxf(sum, 1e-30f);
    #pragma unroll
    for (int c = 0; c < CC; ++c) w2_s[c] = z2[c] * inv;
  }
  __syncthreads();

  // ---- Phase 5: hybrid . target_item, wave-0 reduce ----
  if (t < DD) {
    float hy = 0.f;
    #pragma unroll
    for (int c = 0; c < CC; ++c) hy += w2_s[c] * gvec_s[c][t];
    float ti = item_emb[(size_t)item_inputs[b] * DD + t];
    float prod = hy * ti;
    #pragma unroll
    for (int off = 32; off > 0; off >>= 1)
      prod += __shfl_down(prod, off, 64);
    if (t == 0) out[b] = prod;
  }
}

extern "C" void kernel_launch(void* const* d_in, const int* in_sizes, int n_in,
                              void* d_out, int out_size, void* d_ws, size_t ws_size,
                              hipStream_t stream) {
  const int*   user_inputs   = (const int*)d_in[0];
  const int*   record_inputs = (const int*)d_in[1];
  const int*   item_inputs   = (const int*)d_in[2];
  const int*   item_cat      = (const int*)d_in[3];
  const float* user_emb      = (const float*)d_in[4];
  const float* item_emb      = (const float*)d_in[5];
  const float* W1            = (const float*)d_in[6];
  const float* b1            = (const float*)d_in[7];
  const float* W2            = (const float*)d_in[8];
  const float* b2            = (const float*)d_in[9];
  const float* Wt1           = (const float*)d_in[10];
  const float* bt1           = (const float*)d_in[11];
  const float* Wt2           = (const float*)d_in[12];
  const float* bt2           = (const float*)d_in[13];
  float* out = (float*)d_out;

  din_fwd<<<NB, 256, 0, stream>>>(user_inputs, record_inputs, item_inputs, item_cat,
                                  user_emb, item_emb, W1, b1, W2, b2,
                                  Wt1, bt1, Wt2, bt2, out);
}